// Round 3
// baseline (640.595 us; speedup 1.0000x reference)
//
#include <hip/hip_runtime.h>

// 192^3 FDTD, FUSED single kernel.
//   H2 = H - (DT/mu)*curl(E)        (computed on a haloed tile into LDS)
//   E2 = coefE*E + coefC*curl(H2)   (computed on tile interior from LDS)
// Central differences defined only on the strict interior of ALL three dims;
// curl contribution is zero at any global boundary point.
//
// Tile = 4x4 (i,j) columns x full z (192). LDS holds the three H2 components
// with only the halos each one needs:
//   Hz2: halo in i,j  -> [6][6][192]
//   Hx2: halo in j,k  -> [4][6][194]
//   Hy2: halo in i,k  -> [6][4][194]
// Total 16224 floats = 64,896 B (< 64 KiB) -> 2 blocks/CU.
// Halo points outside the global domain are skipped (never read: E2 at a
// global boundary has curl=0 and reads no neighbors).

#define NXD 192
#define NYD 192
#define NZD 192

static constexpr int   N3    = NXD * NYD * NZD;   // 7,077,888
static constexpr float DTc   = 1e-12f;
static constexpr float INV2D = 500.0f;            // 1/(2*1e-3)

static constexpr int SX = NYD * NZD;  // 36864
static constexpr int SY = NZD;        // 192

static constexpr int TI  = 4, TJ = 4;
static constexpr int NTI = NXD / TI;   // 48
static constexpr int NTJ = NYD / TJ;   // 48
static constexpr int NT  = NTI * NTJ;  // 2304 tiles
static constexpr int BLOCK = 256;

static constexpr int HZ_SZ = 6 * 6 * 192;  // 6912  (i-halo, j-halo)
static constexpr int HX_SZ = 4 * 6 * 194;  // 4656  (j-halo, k-halo)
static constexpr int HY_SZ = 6 * 4 * 194;  // 4656  (i-halo, k-halo)

__global__ __launch_bounds__(BLOCK, 2) void fdtd_fused(
    const float* __restrict__ Ex, const float* __restrict__ Ey, const float* __restrict__ Ez,
    const float* __restrict__ Hx, const float* __restrict__ Hy, const float* __restrict__ Hz,
    const float* __restrict__ eps, const float* __restrict__ mu, const float* __restrict__ sigma,
    float* __restrict__ Ex2, float* __restrict__ Ey2, float* __restrict__ Ez2,
    float* __restrict__ Hx2, float* __restrict__ Hy2, float* __restrict__ Hz2)
{
    __shared__ float sHz[HZ_SZ];
    __shared__ float sHx[HX_SZ];
    __shared__ float sHy[HY_SZ];

    // XCD-aware tile swizzle: XCD n (blocks with b%8==n) owns i-slab n, so
    // +-SX halo fetches stay in that XCD's L2.
    unsigned b    = blockIdx.x;
    unsigned tile = (b & 7u) * (NT / 8) + (b >> 3);
    int ti = (int)(tile / NTJ);
    int tj = (int)(tile % NTJ);
    int gi0 = ti * TI;
    int gj0 = tj * TJ;

    const int tid = threadIdx.x;

    // ---------- Phase 1a: Hz2 over [6][6][192] ----------
    for (int p = tid; p < HZ_SZ; p += BLOCK) {
        int k  = p % 192;
        int t  = p / 192;
        int jj = t % 6;
        int ii = t / 6;
        int i = gi0 + ii - 1;
        int j = gj0 + jj - 1;
        if ((unsigned)i < (unsigned)NXD && (unsigned)j < (unsigned)NYD) {
            int g = i * SX + j * SY + k;
            float curl = 0.0f;
            if (i > 0 && i < NXD - 1 && j > 0 && j < NYD - 1 && k > 0 && k < NZD - 1) {
                curl = ((Ey[g + SX] - Ey[g - SX]) - (Ex[g + SY] - Ex[g - SY])) * INV2D;
            }
            float v = Hz[g] - (DTc / mu[g]) * curl;
            sHz[p] = v;
            if ((unsigned)(ii - 1) < (unsigned)TI && (unsigned)(jj - 1) < (unsigned)TJ)
                Hz2[g] = v;  // tile-owned interior point
        }
    }

    // ---------- Phase 1b: Hx2 over [4][6][194] ----------
    for (int p = tid; p < HX_SZ; p += BLOCK) {
        int kk = p % 194;
        int t  = p / 194;
        int jj = t % 6;
        int ii = t / 6;
        int i = gi0 + ii;       // no i halo
        int j = gj0 + jj - 1;
        int k = kk - 1;
        if ((unsigned)j < (unsigned)NYD && (unsigned)k < (unsigned)NZD) {
            int g = i * SX + j * SY + k;
            float curl = 0.0f;
            if (i > 0 && i < NXD - 1 && j > 0 && j < NYD - 1 && k > 0 && k < NZD - 1) {
                curl = ((Ez[g + SY] - Ez[g - SY]) - (Ey[g + 1] - Ey[g - 1])) * INV2D;
            }
            float v = Hx[g] - (DTc / mu[g]) * curl;
            sHx[p] = v;
            if ((unsigned)(jj - 1) < (unsigned)TJ)
                Hx2[g] = v;
        }
    }

    // ---------- Phase 1c: Hy2 over [6][4][194] ----------
    for (int p = tid; p < HY_SZ; p += BLOCK) {
        int kk = p % 194;
        int t  = p / 194;
        int jj = t % 4;
        int ii = t / 4;
        int i = gi0 + ii - 1;
        int j = gj0 + jj;       // no j halo
        int k = kk - 1;
        if ((unsigned)i < (unsigned)NXD && (unsigned)k < (unsigned)NZD) {
            int g = i * SX + j * SY + k;
            float curl = 0.0f;
            if (i > 0 && i < NXD - 1 && j > 0 && j < NYD - 1 && k > 0 && k < NZD - 1) {
                curl = ((Ex[g + 1] - Ex[g - 1]) - (Ez[g + SX] - Ez[g - SX])) * INV2D;
            }
            float v = Hy[g] - (DTc / mu[g]) * curl;
            sHy[p] = v;
            if ((unsigned)(ii - 1) < (unsigned)TI)
                Hy2[g] = v;
        }
    }

    __syncthreads();

    // ---------- Phase 2: E2 over interior [4][4][192] ----------
    for (int p = tid; p < TI * TJ * 192; p += BLOCK) {
        int k  = p % 192;
        int t  = p / 192;
        int jj = t % TJ;
        int ii = t / TJ;
        int i = gi0 + ii;
        int j = gj0 + jj;
        int g = i * SX + j * SY + k;

        float cx = 0.0f, cy = 0.0f, cz = 0.0f;
        if (i > 0 && i < NXD - 1 && j > 0 && j < NYD - 1 && k > 0 && k < NZD - 1) {
            // LDS halo coords: Hz2 -> (ii+1, jj+1, k); Hx2 -> (ii, jj+1, k+1); Hy2 -> (ii+1, jj, k+1)
            float dHzdy = sHz[((ii + 1) * 6 + (jj + 2)) * 192 + k]
                        - sHz[((ii + 1) * 6 + (jj    )) * 192 + k];
            float dHydz = sHy[((ii + 1) * 4 + jj) * 194 + (k + 2)]
                        - sHy[((ii + 1) * 4 + jj) * 194 + (k    )];
            cx = (dHzdy - dHydz) * INV2D;

            float dHxdz = sHx[(ii * 6 + (jj + 1)) * 194 + (k + 2)]
                        - sHx[(ii * 6 + (jj + 1)) * 194 + (k    )];
            float dHzdx = sHz[((ii + 2) * 6 + (jj + 1)) * 192 + k]
                        - sHz[((ii    ) * 6 + (jj + 1)) * 192 + k];
            cy = (dHxdz - dHzdx) * INV2D;

            float dHydx = sHy[((ii + 2) * 4 + jj) * 194 + (k + 1)]
                        - sHy[((ii    ) * 4 + jj) * 194 + (k + 1)];
            float dHxdy = sHx[(ii * 6 + (jj + 2)) * 194 + (k + 1)]
                        - sHx[(ii * 6 + (jj    )) * 194 + (k + 1)];
            cz = (dHydx - dHxdy) * INV2D;
        }

        float e  = eps[g];
        float sg = sigma[g];
        float hs = sg * (0.5f * DTc) / e;   // sig*DT/(2*eps)
        float r  = 1.0f / (1.0f + hs);
        float cE = (1.0f - hs) * r;
        float cC = DTc * r / e;

        Ex2[g] = cE * Ex[g] + cC * cx;
        Ey2[g] = cE * Ey[g] + cC * cy;
        Ez2[g] = cE * Ez[g] + cC * cz;
    }
}

extern "C" void kernel_launch(void* const* d_in, const int* in_sizes, int n_in,
                              void* d_out, int out_size, void* d_ws, size_t ws_size,
                              hipStream_t stream)
{
    // setup_inputs order: Ex, Ey, Ez, Hx, Hy, Hz, eps, mu, sigma
    const float* Ex    = (const float*)d_in[0];
    const float* Ey    = (const float*)d_in[1];
    const float* Ez    = (const float*)d_in[2];
    const float* Hx    = (const float*)d_in[3];
    const float* Hy    = (const float*)d_in[4];
    const float* Hz    = (const float*)d_in[5];
    const float* eps   = (const float*)d_in[6];
    const float* mu    = (const float*)d_in[7];
    const float* sigma = (const float*)d_in[8];

    // outputs concatenated: ex2, ey2, ez2, hx2, hy2, hz2
    float* out = (float*)d_out;
    float* Ex2 = out + 0 * (size_t)N3;
    float* Ey2 = out + 1 * (size_t)N3;
    float* Ez2 = out + 2 * (size_t)N3;
    float* Hx2 = out + 3 * (size_t)N3;
    float* Hy2 = out + 4 * (size_t)N3;
    float* Hz2 = out + 5 * (size_t)N3;

    fdtd_fused<<<NT, BLOCK, 0, stream>>>(Ex, Ey, Ez, Hx, Hy, Hz, eps, mu, sigma,
                                         Ex2, Ey2, Ez2, Hx2, Hy2, Hz2);
}